// Round 1
// 3012.827 us; speedup vs baseline: 1.3630x; 1.3630x over previous
//
#include <hip/hip_runtime.h>

typedef unsigned short u16;
typedef __bf16 bf16x8 __attribute__((ext_vector_type(8)));
typedef float f32x4 __attribute__((ext_vector_type(4)));

#define T_STEPS 8
#define PLANE 1156            // 34*34 padded spatial positions
#define ROWB 2176             // 34 * 32ch * 2B : bytes per padded row in LDS tile

__device__ __forceinline__ u16 f2bf(float f) {
    unsigned u = __float_as_uint(f);
    return (u16)((u + 0x7fff + ((u >> 16) & 1)) >> 16);
}
__device__ __forceinline__ float sigmoidf(float x) {
    return 1.f / (1.f + expf(-x));
}
// async global->LDS, 16B per lane. LDS dest must be base + lane*16 (linear).
__device__ __forceinline__ void gl_lds16(const void* g, void* l) {
    __builtin_amdgcn_global_load_lds(
        (const __attribute__((address_space(1))) void*)g,
        (__attribute__((address_space(3))) void*)l, 16, 0, 0);
}

// ---------------------------------------------------------------------------
// Repack conv_w (fp32) [2048][1024][3][3] -> bf16 GEMM layout, K reordered
// ci-chunk-major: kt = cc*9 + r  (cc = 32-channel chunk, r = tap).
// dst: [co_blk(16)][kt(144)][quad(4)][co_in(128)][j(8)]
// ---------------------------------------------------------------------------
__global__ void repack_w(const float* __restrict__ w,
                         u16* __restrict__ wx, u16* __restrict__ wh) {
    int g = blockIdx.x * 256 + threadIdx.x;   // 2*16*144*4*128 = 2,359,296
    int co_in = g & 127; g >>= 7;
    int quad  = g & 3;   g >>= 2;
    int kt    = g % 144; g /= 144;
    int co_blk = g & 15; g >>= 4;
    int part = g;                              // 0 = x, 1 = h
    int co = co_blk * 128 + co_in;
    int cc = kt / 9, r = kt - cc * 9;          // chunk, tap (ry*3+rx)
    int ci = cc * 32 + quad * 8;
    const float* src = w + ((size_t)co * 1024 + (size_t)part * 512 + ci) * 9 + r;
    u16* dst = (part ? wh : wx) +
               ((((size_t)co_blk * 144 + kt) * 4 + quad) * 128 + co_in) * 8;
    union { u16 u[8]; uint4 v; } tmp;
#pragma unroll
    for (int j = 0; j < 8; j++) tmp.u[j] = f2bf(src[(size_t)j * 9]);
    *(uint4*)dst = tmp.v;
}

// ---------------------------------------------------------------------------
// x [2][512][8][32][32] f32 -> Xp [b*8+t][34][34][512] bf16 (interior only;
// border pre-zeroed by memset). Reads coalesced along x.
// ---------------------------------------------------------------------------
__global__ __launch_bounds__(256) void pretransform_x(
    const float* __restrict__ x, u16* __restrict__ Xp) {
    const int bt = blockIdx.x >> 5;            // b*8+t
    const int y  = blockIdx.x & 31;
    const int b  = bt >> 3;
    const int xx = threadIdx.x & 31, cg0 = threadIdx.x >> 5;
    const float* src = x + ((size_t)(b * 512) * T_STEPS + (bt & 7)) * 1024
                         + y * 32 + xx;
    u16* dst = Xp + (((size_t)bt * 34 + y + 1) * 34 + (xx + 1)) * 512;
#pragma unroll
    for (int it = 0; it < 8; ++it) {
        const int cig = cg0 + it * 8;          // 0..63 (8-channel group)
        union { u16 u[8]; uint4 v; } pk;
#pragma unroll
        for (int j = 0; j < 8; ++j)
            pk.u[j] = f2bf(src[(size_t)(cig * 8 + j) * 8192]);
        *(uint4*)(dst + cig * 8) = pk.v;
    }
}

// ---------------------------------------------------------------------------
// Implicit-conv GEMM, chunk-staged. Input: padded channel-last bf16.
// 128x128 tile, 512 thr = 8 waves (4m x 2n), 16x16x32 bf16 MFMA.
// Per ci-chunk (32 ch): B-tile [6 rows][34 cols][32 ch] staged once in LDS
// (XOR-swizzled 16B slots), consumed by 9 taps. A staged per tap.
// Single barrier per tap; A dbuf prefetch +1 tap, B dbuf prefetch +1 chunk.
// XMODE: N=4096 covers 2t x 2b (plane=n>>10: b=plane&1, t=t0+(plane>>1)),
//        epilogue stores.  !XMODE: N=2048 (plane=b), epilogue ACCUMULATES.
// ---------------------------------------------------------------------------
template<bool XMODE>
__global__ __launch_bounds__(512) void conv_gemm(
    const u16* __restrict__ Wp, const u16* __restrict__ Xp, int t0,
    float* __restrict__ Z, int ldz) {
    __shared__ __align__(16) u16 As[2][4][128][8];   // 16 KB (dbuf per tap)
    __shared__ __align__(16) u16 Bt[2][6528];        // 25.5 KB (dbuf per chunk)

    const int tid = threadIdx.x;
    const int co_blk = blockIdx.y;
    const int n0 = blockIdx.x * 128;
    const int wave = tid >> 6, lane = tid & 63;
    const int wm = wave >> 1, wn = wave & 1;          // 4 x 2 wave grid
    const int q_l = lane >> 4, m_l = lane & 15;

    const int plane = n0 >> 10;
    const int bb_ = XMODE ? (plane & 1) : plane;
    const int tt  = XMODE ? (t0 + (plane >> 1)) : t0;
    const int pyb = (n0 & 1023) >> 5;                 // first output row (0..28)
    const u16* pbase = Xp + (size_t)(bb_ * T_STEPS + tt) * PLANE * 512;

    // --- B-tile staging constants: 816 16B chunks = [pos(6*34)][slot(4)] ---
    // chunk c -> (pos=c>>2, slot=c&3); source slot pre-swizzled: slot^((x>>1)&3)
    const int c0 = tid;
    const int p0 = c0 >> 2, sl0 = c0 & 3;
    const int yl0 = p0 / 34, xl0 = p0 - yl0 * 34;
    const int src0 = ((pyb + yl0) * 34 + xl0) * 512 + ((sl0 ^ ((xl0 >> 1) & 3)) << 3);
    const int c1 = 512 + tid;
    const int p1 = c1 >> 2, sl1 = c1 & 3;
    const int yl1 = p1 / 34, xl1 = p1 - yl1 * 34;
    const int src1 = ((pyb + yl1) * 34 + xl1) * 512 + ((sl1 ^ ((xl1 >> 1) & 3)) << 3);
    const bool do1 = tid < 304;                       // 816 - 512

    const uint4* Ag = (const uint4*)(Wp + (size_t)co_blk * 144 * 4096) + tid;
    u16* as_me = &As[0][0][0][0] + tid * 8;

    // B-fragment column byte offsets (read-side swizzle matches source swizzle)
    int colb[2][3];
#pragma unroll
    for (int xh = 0; xh < 2; xh++)
#pragma unroll
        for (int rx = 0; rx < 3; rx++) {
            int xl = xh * 16 + m_l + rx;              // 0..33
            colb[xh][rx] = xl * 64 + ((q_l ^ ((xl >> 1) & 3)) << 4);
        }
    const int wnrow = wn * 2 * ROWB;

    f32x4 acc[2][4];
#pragma unroll
    for (int i = 0; i < 2; i++)
#pragma unroll
        for (int j = 0; j < 4; j++) acc[i][j] = (f32x4){0.f, 0.f, 0.f, 0.f};

    // prologue: A(kt=0) -> As[0];  B chunk 0 -> Bt[0]
    gl_lds16(Ag, as_me);
    gl_lds16(pbase + src0, &Bt[0][c0 * 8]);
    if (do1) gl_lds16(pbase + src1, &Bt[0][c1 * 8]);

    for (int cc = 0; cc < 16; ++cc) {
        const int cb = cc & 1;
        const char* btc = (const char*)&Bt[cb][0];
#pragma unroll
        for (int r = 0; r < 9; ++r) {
            const int kt = cc * 9 + r;
            const int ry = r / 3, rx = r % 3;
            // barrier: drains last tap's global_load_lds (vmcnt0) and all
            // waves' LDS reads of the buffers we are about to overwrite.
            __syncthreads();
            if (kt < 143)
                gl_lds16(Ag + (size_t)(kt + 1) * 512,
                         as_me + ((kt + 1) & 1) * 4096);
            if (r == 0 && cc < 15) {
                const u16* gs = pbase + (cc + 1) * 32;   // next ci chunk
                gl_lds16(gs + src0, &Bt[cb ^ 1][c0 * 8]);
                if (do1) gl_lds16(gs + src1, &Bt[cb ^ 1][c1 * 8]);
            }
            const u16* asb = &As[kt & 1][q_l][wm * 32 + m_l][0];
            bf16x8 af0 = *(const bf16x8*)asb;
            bf16x8 af1 = *(const bf16x8*)(asb + 128);
            bf16x8 bf0 = *(const bf16x8*)(btc + wnrow + (0 + ry) * ROWB + colb[0][rx]);
            bf16x8 bf1 = *(const bf16x8*)(btc + wnrow + (0 + ry) * ROWB + colb[1][rx]);
            bf16x8 bf2 = *(const bf16x8*)(btc + wnrow + (1 + ry) * ROWB + colb[0][rx]);
            bf16x8 bf3 = *(const bf16x8*)(btc + wnrow + (1 + ry) * ROWB + colb[1][rx]);
            acc[0][0] = __builtin_amdgcn_mfma_f32_16x16x32_bf16(af0, bf0, acc[0][0], 0, 0, 0);
            acc[0][1] = __builtin_amdgcn_mfma_f32_16x16x32_bf16(af0, bf1, acc[0][1], 0, 0, 0);
            acc[0][2] = __builtin_amdgcn_mfma_f32_16x16x32_bf16(af0, bf2, acc[0][2], 0, 0, 0);
            acc[0][3] = __builtin_amdgcn_mfma_f32_16x16x32_bf16(af0, bf3, acc[0][3], 0, 0, 0);
            acc[1][0] = __builtin_amdgcn_mfma_f32_16x16x32_bf16(af1, bf0, acc[1][0], 0, 0, 0);
            acc[1][1] = __builtin_amdgcn_mfma_f32_16x16x32_bf16(af1, bf1, acc[1][1], 0, 0, 0);
            acc[1][2] = __builtin_amdgcn_mfma_f32_16x16x32_bf16(af1, bf2, acc[1][2], 0, 0, 0);
            acc[1][3] = __builtin_amdgcn_mfma_f32_16x16x32_bf16(af1, bf3, acc[1][3], 0, 0, 0);
        }
    }

    // Epilogue: C/D layout col=lane&15 (n), row=(lane>>4)*4+reg (m)
#pragma unroll
    for (int mt = 0; mt < 2; mt++)
#pragma unroll
        for (int nt = 0; nt < 4; nt++)
#pragma unroll
            for (int reg = 0; reg < 4; reg++) {
                int co = co_blk * 128 + wm * 32 + mt * 16 + q_l * 4 + reg;
                int n  = n0 + wn * 64 + nt * 16 + m_l;
                float* zp = &Z[(size_t)co * ldz + n];
                if (XMODE) *zp = acc[mt][nt][reg];
                else       *zp += acc[mt][nt][reg];
            }
}

// ---------------------------------------------------------------------------
// Gates: fp32 math; z = Zx (x-part, with h-part pre-accumulated for t>0).
// Writes Y into padded channel-last layout via LDS transpose; out coalesced.
// grid: (8 s-tiles of 128, 32 co-tiles of 16, 2 b), 256 threads.
// ---------------------------------------------------------------------------
__global__ __launch_bounds__(256) void gates_kernel(
    const float* __restrict__ zx, int nxoff,
    const float* __restrict__ bias,
    const float* __restrict__ wci, const float* __restrict__ wcf,
    const float* __restrict__ wco,
    float* __restrict__ C, int is_first,
    u16* __restrict__ Yp, int t,
    float* __restrict__ outp) {
    __shared__ u16 Hs[16][136];
    const int tid = threadIdx.x;
    const int s0  = blockIdx.x * 128;
    const int co0 = blockIdx.y * 16;
    const int b   = blockIdx.z;
    const int sl = tid & 127, ch = tid >> 7;
    const int s = s0 + sl;

#pragma unroll
    for (int k = 0; k < 8; ++k) {
        const int co = co0 + k * 2 + ch;
        const size_t zi_ = (size_t)co * 4096 + nxoff + b * 1024 + s;
        float zi = zx[zi_]                       + bias[co];
        float zf = zx[zi_ + (size_t)512 * 4096]  + bias[co + 512];
        float zc = zx[zi_ + (size_t)1024 * 4096] + bias[co + 1024];
        float zo = zx[zi_ + (size_t)1536 * 4096] + bias[co + 1536];
        const size_t ci_ = ((size_t)b * 512 + co) * 1024 + s;
        float Cp = is_first ? 0.f : C[ci_];
        const int ps = co * 1024 + s;
        float gi = sigmoidf(zi + wci[ps] * Cp);
        float gf = sigmoidf(zf + wcf[ps] * Cp);
        float Cn = gf * Cp + gi * fmaxf(zc, 0.f);
        float go = sigmoidf(zo + wco[ps] * Cn);
        float Hn = go * fmaxf(Cn, 0.f);
        C[ci_] = Cn;
        Hs[k * 2 + ch][sl] = f2bf(Hn);
        if (outp) outp[ci_] = sigmoidf(Hn);
    }
    __syncthreads();
    // transpose-write: 16 channels contiguous per spatial position
    const int sl2 = tid & 127, half = tid >> 7;
    const int s2 = s0 + sl2;
    const int yp = (s2 >> 5) + 1, xp = (s2 & 31) + 1;
    u16* dst = Yp + (((size_t)(b * T_STEPS + t) * 34 + yp) * 34 + xp) * 512
                  + co0 + half * 8;
    union { u16 u[8]; uint4 v; } pk;
#pragma unroll
    for (int j = 0; j < 8; ++j) pk.u[j] = Hs[half * 8 + j][sl2];
    *(uint4*)dst = pk.v;
}

// ---------------------------------------------------------------------------
extern "C" void kernel_launch(void* const* d_in, const int* in_sizes, int n_in,
                              void* d_out, int out_size, void* d_ws, size_t ws_size,
                              hipStream_t stream) {
    const float* x = (const float*)d_in[0];

    char* ws = (char*)d_ws;
    size_t off = 0;
    auto carve = [&](size_t bytes) { char* p = ws + off; off += (bytes + 255) & ~(size_t)255; return p; };

    u16*   Wx   = (u16*)  carve((size_t)16 * 144 * 4096 * 2);   // 18.9 MB
    u16*   Wh   = (u16*)  carve((size_t)16 * 144 * 4096 * 2);   // 18.9 MB
    float* Zx   = (float*)carve((size_t)2048 * 4096 * 4);       // 33.6 MB (h accumulates in-place)
    float* Cbuf = (float*)carve((size_t)2 * 512 * 1024 * 4);    //  4.2 MB
    const size_t PADB = (size_t)16 * PLANE * 512 * 2;           // 18.9 MB padded Y/X
    u16*   Yp1  = (u16*)  carve(PADB);
    u16*   Yp2  = (u16*)  carve(PADB);                          // doubles as Xp (layer 0 input)
    (void)ws_size; (void)in_sizes; (void)n_in; (void)out_size;  // ~113 MB total

    hipMemsetAsync(Yp1, 0, PADB, stream);                       // zero borders
    hipMemsetAsync(Yp2, 0, PADB, stream);
    pretransform_x<<<512, 256, 0, stream>>>(x, Yp2);

    for (int l = 0; l < 3; ++l) {
        const float* w    = (const float*)d_in[1 + 5 * l];
        const float* bias = (const float*)d_in[2 + 5 * l];
        const float* wci  = (const float*)d_in[3 + 5 * l];
        const float* wcf  = (const float*)d_in[4 + 5 * l];
        const float* wco  = (const float*)d_in[5 + 5 * l];
        const u16* inl = (l == 0) ? Yp2 : (l == 1 ? Yp1 : Yp2); // layer-1 overwrites Yp2(=Xp) only after Xp fully consumed
        u16* Ycur      = (l == 0) ? Yp1 : (l == 1 ? Yp2 : Yp1);

        repack_w<<<9216, 256, 0, stream>>>(w, Wx, Wh);

        for (int t = 0; t < T_STEPS; ++t) {
            if ((t & 1) == 0)   // x-part for timesteps t, t+1: N = 4096 (store)
                conv_gemm<true><<<dim3(32, 16), 512, 0, stream>>>(
                    Wx, inl, t, Zx, 4096);
            if (t > 0)          // h-part on H_{t-1}: N = 2048, accumulate into Zx
                conv_gemm<false><<<dim3(16, 16), 512, 0, stream>>>(
                    Wh, Ycur, t - 1, Zx + (size_t)(t & 1) * 2048, 4096);
            float* outp = (l == 2 && t == T_STEPS - 1) ? (float*)d_out : nullptr;
            gates_kernel<<<dim3(8, 32, 2), 256, 0, stream>>>(
                Zx, (t & 1) * 2048, bias, wci, wcf, wco,
                Cbuf, (t == 0) ? 1 : 0, Ycur, t, outp);
        }
    }
}

// Round 2
// 2658.990 us; speedup vs baseline: 1.5443x; 1.1331x over previous
//
#include <hip/hip_runtime.h>

typedef unsigned short u16;
typedef __bf16 bf16x8 __attribute__((ext_vector_type(8)));
typedef float f32x4 __attribute__((ext_vector_type(4)));

#define T_STEPS 8
#define PLANE 1156            // 34*34 padded spatial positions
#define ROWB 2176             // 34 * 32ch * 2B : bytes per padded row in LDS tile

__device__ __forceinline__ u16 f2bf(float f) {
    unsigned u = __float_as_uint(f);
    return (u16)((u + 0x7fff + ((u >> 16) & 1)) >> 16);
}
__device__ __forceinline__ float sigmoidf(float x) {
    return 1.f / (1.f + expf(-x));
}
// async global->LDS, 16B per lane. LDS dest must be base + lane*16 (linear).
__device__ __forceinline__ void gl_lds16(const void* g, void* l) {
    __builtin_amdgcn_global_load_lds(
        (const __attribute__((address_space(1))) void*)g,
        (__attribute__((address_space(3))) void*)l, 16, 0, 0);
}

// ---------------------------------------------------------------------------
// Repack conv_w (fp32) [2048][1024][3][3] -> bf16 GEMM layout, K reordered
// ci-chunk-major: kt = cc*9 + r  (cc = 32-channel chunk, r = tap).
// dst: [co_blk(16)][kt(144)][quad(4)][co_in(128)][j(8)]
// ---------------------------------------------------------------------------
__global__ void repack_w(const float* __restrict__ w,
                         u16* __restrict__ wx, u16* __restrict__ wh) {
    int g = blockIdx.x * 256 + threadIdx.x;   // 2*16*144*4*128 = 2,359,296
    int co_in = g & 127; g >>= 7;
    int quad  = g & 3;   g >>= 2;
    int kt    = g % 144; g /= 144;
    int co_blk = g & 15; g >>= 4;
    int part = g;                              // 0 = x, 1 = h
    int co = co_blk * 128 + co_in;
    int cc = kt / 9, r = kt - cc * 9;          // chunk, tap (ry*3+rx)
    int ci = cc * 32 + quad * 8;
    const float* src = w + ((size_t)co * 1024 + (size_t)part * 512 + ci) * 9 + r;
    u16* dst = (part ? wh : wx) +
               ((((size_t)co_blk * 144 + kt) * 4 + quad) * 128 + co_in) * 8;
    union { u16 u[8]; uint4 v; } tmp;
#pragma unroll
    for (int j = 0; j < 8; j++) tmp.u[j] = f2bf(src[(size_t)j * 9]);
    *(uint4*)dst = tmp.v;
}

// ---------------------------------------------------------------------------
// x [2][512][8][32][32] f32 -> Xp [b*8+t][34][34][512] bf16 (interior only;
// border pre-zeroed by memset). Reads coalesced along x.
// ---------------------------------------------------------------------------
__global__ __launch_bounds__(256) void pretransform_x(
    const float* __restrict__ x, u16* __restrict__ Xp) {
    const int bt = blockIdx.x >> 5;            // b*8+t
    const int y  = blockIdx.x & 31;
    const int b  = bt >> 3;
    const int xx = threadIdx.x & 31, cg0 = threadIdx.x >> 5;
    const float* src = x + ((size_t)(b * 512) * T_STEPS + (bt & 7)) * 1024
                         + y * 32 + xx;
    u16* dst = Xp + (((size_t)bt * 34 + y + 1) * 34 + (xx + 1)) * 512;
#pragma unroll
    for (int it = 0; it < 8; ++it) {
        const int cig = cg0 + it * 8;          // 0..63 (8-channel group)
        union { u16 u[8]; uint4 v; } pk;
#pragma unroll
        for (int j = 0; j < 8; ++j)
            pk.u[j] = f2bf(src[(size_t)(cig * 8 + j) * 8192]);
        *(uint4*)(dst + cig * 8) = pk.v;
    }
}

// ---------------------------------------------------------------------------
// Implicit-conv GEMM, chunk-staged, counted-vmcnt pipeline (T3+T4+T5).
// 128x128 tile, 512 thr = 8 waves (4m x 2n), 16x16x32 bf16 MFMA.
// A: 4-deep tap buffers, prefetch +2 taps.  B: per-chunk dbuf, prefetch +1
// chunk (issued at r==1).  One raw s_barrier per tap, vmcnt never drained
// to 0 in the main loop.  Hazards:
//   RAW: vmcnt(N) before barrier guarantees each wave's own loads for the
//        consumed buffers retired; barrier makes that global.
//   WAR: a buffer written at phase k was last ds_read at phase k-2; those
//        reads complete (lgkmcnt before MFMA) before barrier k-1, which
//        precedes phase k's issue.  B issued at r==1 for the same reason.
// Per-wave issue counts: waves 0-4 issue 2 B-loads/chunk, waves 5-7 issue 1.
// XCD swizzle: each XCD owns 2 co_blks x all n -> A slice (2.4MB) L2-resident.
// ---------------------------------------------------------------------------
template<bool XMODE>
__global__ __launch_bounds__(512) void conv_gemm(
    const u16* __restrict__ Wp, const u16* __restrict__ Xp, int t0,
    float* __restrict__ Z, int ldz) {
    __shared__ __align__(16) u16 As[4][4][128][8];   // 32 KB: 4 tap-deep bufs
    __shared__ __align__(16) u16 Bt[2][6528];        // 26 KB: chunk dbuf

    const int tid = threadIdx.x;
    // --- XCD co-clustered swizzle (bijective, nwg%8==0) ---
    const int GX  = XMODE ? 32 : 16;
    const int nwg = GX * 16;
    const int bid = blockIdx.y * GX + blockIdx.x;
    const int swz = (bid & 7) * (nwg >> 3) + (bid >> 3);
    const int co_blk = swz / GX;                      // GX is 2^k: shift
    const int nblk   = swz - co_blk * GX;
    const int n0 = nblk * 128;

    const int wave = tid >> 6, lane = tid & 63;
    const int wm = wave >> 1, wn = wave & 1;          // 4 x 2 wave grid
    const int q_l = lane >> 4, m_l = lane & 15;

    const int plane = n0 >> 10;
    const int bb_ = XMODE ? (plane & 1) : plane;
    const int tt  = XMODE ? (t0 + (plane >> 1)) : t0;
    const int pyb = (n0 & 1023) >> 5;                 // first output row (0..28)
    const u16* pbase = Xp + (size_t)(bb_ * T_STEPS + tt) * PLANE * 512;

    // --- B-tile staging: 816 16B chunks = [pos(6*34)][slot(4)] ---
    // chunk c -> (pos=c>>2, slot=c&3); source slot pre-swizzled: slot^((x>>1)&3)
    const int c0 = tid;
    const int p0 = c0 >> 2, sl0 = c0 & 3;
    const int yl0 = p0 / 34, xl0 = p0 - yl0 * 34;
    const int src0 = ((pyb + yl0) * 34 + xl0) * 512 + ((sl0 ^ ((xl0 >> 1) & 3)) << 3);
    const int c1 = 512 + tid;
    const int p1 = c1 >> 2, sl1 = c1 & 3;
    const int yl1 = p1 / 34, xl1 = p1 - yl1 * 34;
    const int src1 = ((pyb + yl1) * 34 + xl1) * 512 + ((sl1 ^ ((xl1 >> 1) & 3)) << 3);
    const bool do1 = tid < 304;                       // 816 - 512

    const uint4* Ag = (const uint4*)(Wp + (size_t)co_blk * 144 * 4096) + tid;
    u16* as_me = &As[0][0][0][0] + tid * 8;

    // B-fragment column byte offsets (read swizzle matches source swizzle)
    int colb[2][3];
#pragma unroll
    for (int xh = 0; xh < 2; xh++)
#pragma unroll
        for (int rx = 0; rx < 3; rx++) {
            int xl = xh * 16 + m_l + rx;              // 0..33
            colb[xh][rx] = xl * 64 + ((q_l ^ ((xl >> 1) & 3)) << 4);
        }
    const int wnrow = wn * 2 * ROWB;

    f32x4 acc[2][4];
#pragma unroll
    for (int i = 0; i < 2; i++)
#pragma unroll
        for (int j = 0; j < 4; j++) acc[i][j] = (f32x4){0.f, 0.f, 0.f, 0.f};

    // prologue: B(0) first, then A(0)->buf0, A(1)->buf1 (order matters for
    // the vmcnt counts: B(0) is oldest, retires before A(0)).
    gl_lds16(pbase + src0, &Bt[0][c0 * 8]);
    if (do1) gl_lds16(pbase + src1, &Bt[0][c1 * 8]);
    gl_lds16(Ag, as_me);
    gl_lds16(Ag + 512, as_me + 4096);

    for (int cc = 0; cc < 16; ++cc) {
        const int cb = cc & 1;
        const char* btc = (const char*)&Bt[cb][0];
        const uint4* AgC = Ag + (size_t)cc * 4608;    // 9 taps * 512
#pragma unroll
        for (int r = 0; r < 9; ++r) {
            // ---- issue stage (A +2 taps; B +1 chunk at r==1) ----
            if (cc < 15 || r < 7)
                gl_lds16(AgC + (r + 2) * 512,
                         as_me + ((cc + r + 2) & 3) * 4096);
            if (r == 1 && cc < 15) {
                const u16* gs = pbase + (cc + 1) * 32;
                gl_lds16(gs + src0, &Bt[cb ^ 1][c0 * 8]);
                if (do1) gl_lds16(gs + src1, &Bt[cb ^ 1][c1 * 8]);
            }
            // ---- counted wait (exact per-phase, per-wave) + barrier ----
            if (r == 1 || r == 2) {
                if (cc < 15) {
                    if (wave < 5) asm volatile("s_waitcnt vmcnt(4)" ::: "memory");
                    else          asm volatile("s_waitcnt vmcnt(3)" ::: "memory");
                } else {
                    asm volatile("s_waitcnt vmcnt(2)" ::: "memory");
                }
            } else if (r == 7) {
                if (cc == 15) asm volatile("s_waitcnt vmcnt(1)" ::: "memory");
                else          asm volatile("s_waitcnt vmcnt(2)" ::: "memory");
            } else if (r == 8) {
                if (cc == 15) asm volatile("s_waitcnt vmcnt(0)" ::: "memory");
                else          asm volatile("s_waitcnt vmcnt(2)" ::: "memory");
            } else {
                asm volatile("s_waitcnt vmcnt(2)" ::: "memory");
            }
            __builtin_amdgcn_s_barrier();
            asm volatile("" ::: "memory");            // no LDS reads above this

            // ---- consume tap kt = cc*9+r ----
            const int ry = r / 3, rx = r % 3;
            const u16* asb = &As[(cc + r) & 3][q_l][wm * 32 + m_l][0];
            bf16x8 af0 = *(const bf16x8*)asb;
            bf16x8 af1 = *(const bf16x8*)(asb + 128);
            bf16x8 bf0 = *(const bf16x8*)(btc + wnrow + (0 + ry) * ROWB + colb[0][rx]);
            bf16x8 bf1 = *(const bf16x8*)(btc + wnrow + (0 + ry) * ROWB + colb[1][rx]);
            bf16x8 bf2 = *(const bf16x8*)(btc + wnrow + (1 + ry) * ROWB + colb[0][rx]);
            bf16x8 bf3 = *(const bf16x8*)(btc + wnrow + (1 + ry) * ROWB + colb[1][rx]);
            __builtin_amdgcn_s_setprio(1);
            acc[0][0] = __builtin_amdgcn_mfma_f32_16x16x32_bf16(af0, bf0, acc[0][0], 0, 0, 0);
            acc[0][1] = __builtin_amdgcn_mfma_f32_16x16x32_bf16(af0, bf1, acc[0][1], 0, 0, 0);
            acc[0][2] = __builtin_amdgcn_mfma_f32_16x16x32_bf16(af0, bf2, acc[0][2], 0, 0, 0);
            acc[0][3] = __builtin_amdgcn_mfma_f32_16x16x32_bf16(af0, bf3, acc[0][3], 0, 0, 0);
            acc[1][0] = __builtin_amdgcn_mfma_f32_16x16x32_bf16(af1, bf0, acc[1][0], 0, 0, 0);
            acc[1][1] = __builtin_amdgcn_mfma_f32_16x16x32_bf16(af1, bf1, acc[1][1], 0, 0, 0);
            acc[1][2] = __builtin_amdgcn_mfma_f32_16x16x32_bf16(af1, bf2, acc[1][2], 0, 0, 0);
            acc[1][3] = __builtin_amdgcn_mfma_f32_16x16x32_bf16(af1, bf3, acc[1][3], 0, 0, 0);
            __builtin_amdgcn_s_setprio(0);
        }
    }

    // Epilogue: C/D layout col=lane&15 (n), row=(lane>>4)*4+reg (m)
#pragma unroll
    for (int mt = 0; mt < 2; mt++)
#pragma unroll
        for (int nt = 0; nt < 4; nt++)
#pragma unroll
            for (int reg = 0; reg < 4; reg++) {
                int co = co_blk * 128 + wm * 32 + mt * 16 + q_l * 4 + reg;
                int n  = n0 + wn * 64 + nt * 16 + m_l;
                float* zp = &Z[(size_t)co * ldz + n];
                if (XMODE) *zp = acc[mt][nt][reg];
                else       *zp += acc[mt][nt][reg];
            }
}

// ---------------------------------------------------------------------------
// Gates: fp32 math; z = Zx (x-part, with h-part pre-accumulated for t>0).
// Writes Y into padded channel-last layout via LDS transpose; out coalesced.
// grid: (8 s-tiles of 128, 32 co-tiles of 16, 2 b), 256 threads.
// ---------------------------------------------------------------------------
__global__ __launch_bounds__(256) void gates_kernel(
    const float* __restrict__ zx, int nxoff,
    const float* __restrict__ bias,
    const float* __restrict__ wci, const float* __restrict__ wcf,
    const float* __restrict__ wco,
    float* __restrict__ C, int is_first,
    u16* __restrict__ Yp, int t,
    float* __restrict__ outp) {
    __shared__ u16 Hs[16][136];
    const int tid = threadIdx.x;
    const int s0  = blockIdx.x * 128;
    const int co0 = blockIdx.y * 16;
    const int b   = blockIdx.z;
    const int sl = tid & 127, ch = tid >> 7;
    const int s = s0 + sl;

#pragma unroll
    for (int k = 0; k < 8; ++k) {
        const int co = co0 + k * 2 + ch;
        const size_t zi_ = (size_t)co * 4096 + nxoff + b * 1024 + s;
        float zi = zx[zi_]                       + bias[co];
        float zf = zx[zi_ + (size_t)512 * 4096]  + bias[co + 512];
        float zc = zx[zi_ + (size_t)1024 * 4096] + bias[co + 1024];
        float zo = zx[zi_ + (size_t)1536 * 4096] + bias[co + 1536];
        const size_t ci_ = ((size_t)b * 512 + co) * 1024 + s;
        float Cp = is_first ? 0.f : C[ci_];
        const int ps = co * 1024 + s;
        float gi = sigmoidf(zi + wci[ps] * Cp);
        float gf = sigmoidf(zf + wcf[ps] * Cp);
        float Cn = gf * Cp + gi * fmaxf(zc, 0.f);
        float go = sigmoidf(zo + wco[ps] * Cn);
        float Hn = go * fmaxf(Cn, 0.f);
        C[ci_] = Cn;
        Hs[k * 2 + ch][sl] = f2bf(Hn);
        if (outp) outp[ci_] = sigmoidf(Hn);
    }
    __syncthreads();
    // transpose-write: 16 channels contiguous per spatial position
    const int sl2 = tid & 127, half = tid >> 7;
    const int s2 = s0 + sl2;
    const int yp = (s2 >> 5) + 1, xp = (s2 & 31) + 1;
    u16* dst = Yp + (((size_t)(b * T_STEPS + t) * 34 + yp) * 34 + xp) * 512
                  + co0 + half * 8;
    union { u16 u[8]; uint4 v; } pk;
#pragma unroll
    for (int j = 0; j < 8; ++j) pk.u[j] = Hs[half * 8 + j][sl2];
    *(uint4*)dst = pk.v;
}

// ---------------------------------------------------------------------------
extern "C" void kernel_launch(void* const* d_in, const int* in_sizes, int n_in,
                              void* d_out, int out_size, void* d_ws, size_t ws_size,
                              hipStream_t stream) {
    const float* x = (const float*)d_in[0];

    char* ws = (char*)d_ws;
    size_t off = 0;
    auto carve = [&](size_t bytes) { char* p = ws + off; off += (bytes + 255) & ~(size_t)255; return p; };

    u16*   Wx   = (u16*)  carve((size_t)16 * 144 * 4096 * 2);   // 18.9 MB
    u16*   Wh   = (u16*)  carve((size_t)16 * 144 * 4096 * 2);   // 18.9 MB
    float* Zx   = (float*)carve((size_t)2048 * 4096 * 4);       // 33.6 MB (h accumulates in-place)
    float* Cbuf = (float*)carve((size_t)2 * 512 * 1024 * 4);    //  4.2 MB
    const size_t PADB = (size_t)16 * PLANE * 512 * 2;           // 18.9 MB padded Y/X
    u16*   Yp1  = (u16*)  carve(PADB);
    u16*   Yp2  = (u16*)  carve(PADB);                          // doubles as Xp (layer 0 input)
    (void)ws_size; (void)in_sizes; (void)n_in; (void)out_size;  // ~113 MB total

    hipMemsetAsync(Yp1, 0, PADB, stream);                       // zero borders
    hipMemsetAsync(Yp2, 0, PADB, stream);
    pretransform_x<<<512, 256, 0, stream>>>(x, Yp2);

    for (int l = 0; l < 3; ++l) {
        const float* w    = (const float*)d_in[1 + 5 * l];
        const float* bias = (const float*)d_in[2 + 5 * l];
        const float* wci  = (const float*)d_in[3 + 5 * l];
        const float* wcf  = (const float*)d_in[4 + 5 * l];
        const float* wco  = (const float*)d_in[5 + 5 * l];
        const u16* inl = (l == 0) ? Yp2 : (l == 1 ? Yp1 : Yp2); // layer-1 overwrites Yp2(=Xp) only after Xp fully consumed
        u16* Ycur      = (l == 0) ? Yp1 : (l == 1 ? Yp2 : Yp1);

        repack_w<<<9216, 256, 0, stream>>>(w, Wx, Wh);

        for (int t = 0; t < T_STEPS; ++t) {
            if ((t & 1) == 0)   // x-part for timesteps t, t+1: N = 4096 (store)
                conv_gemm<true><<<dim3(32, 16), 512, 0, stream>>>(
                    Wx, inl, t, Zx, 4096);
            if (t > 0)          // h-part on H_{t-1}: N = 2048, accumulate into Zx
                conv_gemm<false><<<dim3(16, 16), 512, 0, stream>>>(
                    Wh, Ycur, t - 1, Zx + (size_t)(t & 1) * 2048, 4096);
            float* outp = (l == 2 && t == T_STEPS - 1) ? (float*)d_out : nullptr;
            gates_kernel<<<dim3(8, 32, 2), 256, 0, stream>>>(
                Zx, (t & 1) * 2048, bias, wci, wcf, wco,
                Cbuf, (t == 0) ? 1 : 0, Ycur, t, outp);
        }
    }
}

// Round 3
// 2265.625 us; speedup vs baseline: 1.8125x; 1.1736x over previous
//
#include <hip/hip_runtime.h>

typedef unsigned short u16;
typedef __bf16 bf16x8 __attribute__((ext_vector_type(8)));
typedef float f32x4 __attribute__((ext_vector_type(4)));

#define T_STEPS 8
#define PLANE 1156            // 34*34 padded spatial positions
#define ROWB 2176             // 34 * 32ch * 2B : bytes per padded row in LDS tile

__device__ __forceinline__ u16 f2bf(float f) {
    unsigned u = __float_as_uint(f);
    return (u16)((u + 0x7fff + ((u >> 16) & 1)) >> 16);
}
__device__ __forceinline__ float sigmoidf(float x) {
    return 1.f / (1.f + expf(-x));
}
// async global->LDS, 16B per lane. LDS dest must be base + lane*16 (linear).
__device__ __forceinline__ void gl_lds16(const void* g, void* l) {
    __builtin_amdgcn_global_load_lds(
        (const __attribute__((address_space(1))) void*)g,
        (__attribute__((address_space(3))) void*)l, 16, 0, 0);
}

// ---------------------------------------------------------------------------
// Repack conv_w (fp32) [2048][1024][3][3] -> bf16 GEMM layout, K reordered
// ci-chunk-major: kt = cc*9 + r  (cc = 32-channel chunk, r = tap).
// dst: [co_blk(16)][kt(144)][quad(4)][co_in(128)][j(8)]
// ---------------------------------------------------------------------------
__global__ void repack_w(const float* __restrict__ w,
                         u16* __restrict__ wx, u16* __restrict__ wh) {
    int g = blockIdx.x * 256 + threadIdx.x;   // 2*16*144*4*128 = 2,359,296
    int co_in = g & 127; g >>= 7;
    int quad  = g & 3;   g >>= 2;
    int kt    = g % 144; g /= 144;
    int co_blk = g & 15; g >>= 4;
    int part = g;                              // 0 = x, 1 = h
    int co = co_blk * 128 + co_in;
    int cc = kt / 9, r = kt - cc * 9;          // chunk, tap (ry*3+rx)
    int ci = cc * 32 + quad * 8;
    const float* src = w + ((size_t)co * 1024 + (size_t)part * 512 + ci) * 9 + r;
    u16* dst = (part ? wh : wx) +
               ((((size_t)co_blk * 144 + kt) * 4 + quad) * 128 + co_in) * 8;
    union { u16 u[8]; uint4 v; } tmp;
#pragma unroll
    for (int j = 0; j < 8; j++) tmp.u[j] = f2bf(src[(size_t)j * 9]);
    *(uint4*)dst = tmp.v;
}

// ---------------------------------------------------------------------------
// x [2][512][8][32][32] f32 -> Xp [b*8+t][34][34][512] bf16 (interior only;
// border pre-zeroed by memset). Reads coalesced along x.
// ---------------------------------------------------------------------------
__global__ __launch_bounds__(256) void pretransform_x(
    const float* __restrict__ x, u16* __restrict__ Xp) {
    const int bt = blockIdx.x >> 5;            // b*8+t
    const int y  = blockIdx.x & 31;
    const int b  = bt >> 3;
    const int xx = threadIdx.x & 31, cg0 = threadIdx.x >> 5;
    const float* src = x + ((size_t)(b * 512) * T_STEPS + (bt & 7)) * 1024
                         + y * 32 + xx;
    u16* dst = Xp + (((size_t)bt * 34 + y + 1) * 34 + (xx + 1)) * 512;
#pragma unroll
    for (int it = 0; it < 8; ++it) {
        const int cig = cg0 + it * 8;          // 0..63 (8-channel group)
        union { u16 u[8]; uint4 v; } pk;
#pragma unroll
        for (int j = 0; j < 8; ++j)
            pk.u[j] = f2bf(src[(size_t)(cig * 8 + j) * 8192]);
        *(uint4*)(dst + cig * 8) = pk.v;
    }
}

// ---------------------------------------------------------------------------
// Implicit-conv GEMM.  A (weights) bypasses LDS: loaded global->VGPR in a
// 3-deep register ring, prefetched +2 taps (L2-resident via XCD swizzle;
// compiler inserts precise vmcnt for register deps).  LDS holds only the
// B chunk tile (dbuf), staged by global_load_lds and consumed by all 9 taps.
// Sync: ONE vmcnt(4) + s_barrier per chunk (r==0):
//   RAW: own B(cc) loads are >=14 VMEM instrs older than the newest 4
//        (A prefetch pair x2) -> vmcnt(4) drains them; barrier makes global.
//   WAR: B(cc+1) (issued at r==1, after the barrier) overwrites the buffer
//        last read in chunk cc-1, whose reads precede the barrier.
// 128x128 tile, 512 thr = 8 waves (4m x 2n), 16x16x32 bf16 MFMA.
// ---------------------------------------------------------------------------
template<bool XMODE>
__global__ __launch_bounds__(512, 4) void conv_gemm(
    const u16* __restrict__ Wp, const u16* __restrict__ Xp, int t0,
    float* __restrict__ Z, int ldz) {
    __shared__ __align__(16) u16 Bt[2][6528];        // 25.5 KB: chunk dbuf

    const int tid = threadIdx.x;
    // --- XCD co-clustered swizzle (bijective, nwg%8==0) ---
    const int GX  = XMODE ? 32 : 16;
    const int nwg = GX * 16;
    const int bid = blockIdx.y * GX + blockIdx.x;
    const int swz = (bid & 7) * (nwg >> 3) + (bid >> 3);
    const int co_blk = swz / GX;
    const int nblk   = swz - co_blk * GX;
    const int n0 = nblk * 128;

    const int wave = tid >> 6, lane = tid & 63;
    const int wm = wave >> 1, wn = wave & 1;          // 4 x 2 wave grid
    const int q_l = lane >> 4, m_l = lane & 15;

    const int plane = n0 >> 10;
    const int bb_ = XMODE ? (plane & 1) : plane;
    const int tt  = XMODE ? (t0 + (plane >> 1)) : t0;
    const int pyb = (n0 & 1023) >> 5;                 // first output row (0..28)
    const u16* pbase = Xp + (size_t)(bb_ * T_STEPS + tt) * PLANE * 512;

    // --- B-tile staging: 816 16B chunks = [pos(6*34)][slot(4)] ---
    const int c0 = tid;
    const int p0 = c0 >> 2, sl0 = c0 & 3;
    const int yl0 = p0 / 34, xl0 = p0 - yl0 * 34;
    const int src0 = ((pyb + yl0) * 34 + xl0) * 512 + ((sl0 ^ ((xl0 >> 1) & 3)) << 3);
    const int c1 = 512 + tid;
    const int p1 = c1 >> 2, sl1 = c1 & 3;
    const int yl1 = p1 / 34, xl1 = p1 - yl1 * 34;
    const int src1 = ((pyb + yl1) * 34 + xl1) * 512 + ((sl1 ^ ((xl1 >> 1) & 3)) << 3);
    const bool do1 = tid < 304;                       // 816 - 512

    // A-fragment pointer: per-thread 16B at [kt][q_l][wm*32+mt*16+m_l]
    const bf16x8* Aq = (const bf16x8*)(const void*)
        ((const uint4*)(Wp + (size_t)co_blk * 144 * 4096)
         + (q_l * 128 + wm * 32 + m_l));

    // B-fragment column byte offsets (read swizzle matches source swizzle)
    int colb[2][3];
#pragma unroll
    for (int xh = 0; xh < 2; xh++)
#pragma unroll
        for (int rx = 0; rx < 3; rx++) {
            int xl = xh * 16 + m_l + rx;              // 0..33
            colb[xh][rx] = xl * 64 + ((q_l ^ ((xl >> 1) & 3)) << 4);
        }
    const int wnrow = wn * 2 * ROWB;

    f32x4 acc[2][4];
#pragma unroll
    for (int i = 0; i < 2; i++)
#pragma unroll
        for (int j = 0; j < 4; j++) acc[i][j] = (f32x4){0.f, 0.f, 0.f, 0.f};

    // prologue: B(0) staged; A(0),A(1) into ring slots 0,1
    gl_lds16(pbase + src0, &Bt[0][c0 * 8]);
    if (do1) gl_lds16(pbase + src1, &Bt[0][c1 * 8]);
    bf16x8 areg[3][2];
    areg[0][0] = Aq[0];          areg[0][1] = Aq[16];
    areg[1][0] = Aq[512];        areg[1][1] = Aq[512 + 16];

    for (int cc = 0; cc < 16; ++cc) {
        const int cb = cc & 1;
        const char* btc = (const char*)&Bt[cb][0];
#pragma unroll
        for (int r = 0; r < 9; ++r) {
            const int kt = cc * 9 + r;
            if (r == 0) {
                // pin prior chunk's LDS reads above; drain own B(cc) loads
                asm volatile("" ::: "memory");
                asm volatile("s_waitcnt vmcnt(4)" ::: "memory");
                __builtin_amdgcn_s_barrier();
                asm volatile("" ::: "memory");        // no LDS reads hoist above
            }
            // issue A(kt+2) into ring slot (static index under unroll)
            if (cc < 15 || r < 7) {
                areg[(r + 2) % 3][0] = Aq[(size_t)(kt + 2) * 512];
                areg[(r + 2) % 3][1] = Aq[(size_t)(kt + 2) * 512 + 16];
            }
            // issue next B chunk (after the chunk barrier -> WAR-safe)
            if (r == 1 && cc < 15) {
                const u16* gs = pbase + (cc + 1) * 32;
                gl_lds16(gs + src0, &Bt[cb ^ 1][c0 * 8]);
                if (do1) gl_lds16(gs + src1, &Bt[cb ^ 1][c1 * 8]);
            }
            const int ry = r / 3, rx = r % 3;
            bf16x8 af0 = areg[r % 3][0];
            bf16x8 af1 = areg[r % 3][1];
            bf16x8 bf0 = *(const bf16x8*)(btc + wnrow + (0 + ry) * ROWB + colb[0][rx]);
            bf16x8 bf1 = *(const bf16x8*)(btc + wnrow + (0 + ry) * ROWB + colb[1][rx]);
            bf16x8 bf2 = *(const bf16x8*)(btc + wnrow + (1 + ry) * ROWB + colb[0][rx]);
            bf16x8 bf3 = *(const bf16x8*)(btc + wnrow + (1 + ry) * ROWB + colb[1][rx]);
            __builtin_amdgcn_s_setprio(1);
            acc[0][0] = __builtin_amdgcn_mfma_f32_16x16x32_bf16(af0, bf0, acc[0][0], 0, 0, 0);
            acc[0][1] = __builtin_amdgcn_mfma_f32_16x16x32_bf16(af0, bf1, acc[0][1], 0, 0, 0);
            acc[0][2] = __builtin_amdgcn_mfma_f32_16x16x32_bf16(af0, bf2, acc[0][2], 0, 0, 0);
            acc[0][3] = __builtin_amdgcn_mfma_f32_16x16x32_bf16(af0, bf3, acc[0][3], 0, 0, 0);
            acc[1][0] = __builtin_amdgcn_mfma_f32_16x16x32_bf16(af1, bf0, acc[1][0], 0, 0, 0);
            acc[1][1] = __builtin_amdgcn_mfma_f32_16x16x32_bf16(af1, bf1, acc[1][1], 0, 0, 0);
            acc[1][2] = __builtin_amdgcn_mfma_f32_16x16x32_bf16(af1, bf2, acc[1][2], 0, 0, 0);
            acc[1][3] = __builtin_amdgcn_mfma_f32_16x16x32_bf16(af1, bf3, acc[1][3], 0, 0, 0);
            __builtin_amdgcn_s_setprio(0);
        }
    }

    // Epilogue: C/D layout col=lane&15 (n), row=(lane>>4)*4+reg (m)
#pragma unroll
    for (int mt = 0; mt < 2; mt++)
#pragma unroll
        for (int nt = 0; nt < 4; nt++)
#pragma unroll
            for (int reg = 0; reg < 4; reg++) {
                int co = co_blk * 128 + wm * 32 + mt * 16 + q_l * 4 + reg;
                int n  = n0 + wn * 64 + nt * 16 + m_l;
                float* zp = &Z[(size_t)co * ldz + n];
                if (XMODE) *zp = acc[mt][nt][reg];
                else       *zp += acc[mt][nt][reg];
            }
}

// ---------------------------------------------------------------------------
// Gates: fp32 math; z = Zx (x-part, with h-part pre-accumulated for t>0).
// Writes Y into padded channel-last layout via LDS transpose; out coalesced.
// grid: (8 s-tiles of 128, 32 co-tiles of 16, 2 b), 256 threads.
// ---------------------------------------------------------------------------
__global__ __launch_bounds__(256) void gates_kernel(
    const float* __restrict__ zx, int nxoff,
    const float* __restrict__ bias,
    const float* __restrict__ wci, const float* __restrict__ wcf,
    const float* __restrict__ wco,
    float* __restrict__ C, int is_first,
    u16* __restrict__ Yp, int t,
    float* __restrict__ outp) {
    __shared__ u16 Hs[16][136];
    const int tid = threadIdx.x;
    const int s0  = blockIdx.x * 128;
    const int co0 = blockIdx.y * 16;
    const int b   = blockIdx.z;
    const int sl = tid & 127, ch = tid >> 7;
    const int s = s0 + sl;

#pragma unroll
    for (int k = 0; k < 8; ++k) {
        const int co = co0 + k * 2 + ch;
        const size_t zi_ = (size_t)co * 4096 + nxoff + b * 1024 + s;
        float zi = zx[zi_]                       + bias[co];
        float zf = zx[zi_ + (size_t)512 * 4096]  + bias[co + 512];
        float zc = zx[zi_ + (size_t)1024 * 4096] + bias[co + 1024];
        float zo = zx[zi_ + (size_t)1536 * 4096] + bias[co + 1536];
        const size_t ci_ = ((size_t)b * 512 + co) * 1024 + s;
        float Cp = is_first ? 0.f : C[ci_];
        const int ps = co * 1024 + s;
        float gi = sigmoidf(zi + wci[ps] * Cp);
        float gf = sigmoidf(zf + wcf[ps] * Cp);
        float Cn = gf * Cp + gi * fmaxf(zc, 0.f);
        float go = sigmoidf(zo + wco[ps] * Cn);
        float Hn = go * fmaxf(Cn, 0.f);
        C[ci_] = Cn;
        Hs[k * 2 + ch][sl] = f2bf(Hn);
        if (outp) outp[ci_] = sigmoidf(Hn);
    }
    __syncthreads();
    // transpose-write: 16 channels contiguous per spatial position
    const int sl2 = tid & 127, half = tid >> 7;
    const int s2 = s0 + sl2;
    const int yp = (s2 >> 5) + 1, xp = (s2 & 31) + 1;
    u16* dst = Yp + (((size_t)(b * T_STEPS + t) * 34 + yp) * 34 + xp) * 512
                  + co0 + half * 8;
    union { u16 u[8]; uint4 v; } pk;
#pragma unroll
    for (int j = 0; j < 8; ++j) pk.u[j] = Hs[half * 8 + j][sl2];
    *(uint4*)dst = pk.v;
}

// ---------------------------------------------------------------------------
extern "C" void kernel_launch(void* const* d_in, const int* in_sizes, int n_in,
                              void* d_out, int out_size, void* d_ws, size_t ws_size,
                              hipStream_t stream) {
    const float* x = (const float*)d_in[0];

    char* ws = (char*)d_ws;
    size_t off = 0;
    auto carve = [&](size_t bytes) { char* p = ws + off; off += (bytes + 255) & ~(size_t)255; return p; };

    u16*   Wx   = (u16*)  carve((size_t)16 * 144 * 4096 * 2);   // 18.9 MB
    u16*   Wh   = (u16*)  carve((size_t)16 * 144 * 4096 * 2);   // 18.9 MB
    float* Zx   = (float*)carve((size_t)2048 * 4096 * 4);       // 33.6 MB (h accumulates in-place)
    float* Cbuf = (float*)carve((size_t)2 * 512 * 1024 * 4);    //  4.2 MB
    const size_t PADB = (size_t)16 * PLANE * 512 * 2;           // 18.9 MB padded Y/X
    u16*   Yp1  = (u16*)  carve(PADB);
    u16*   Yp2  = (u16*)  carve(PADB);                          // doubles as Xp (layer 0 input)
    (void)ws_size; (void)in_sizes; (void)n_in; (void)out_size;  // ~113 MB total

    hipMemsetAsync(Yp1, 0, PADB, stream);                       // zero borders
    hipMemsetAsync(Yp2, 0, PADB, stream);
    pretransform_x<<<512, 256, 0, stream>>>(x, Yp2);

    for (int l = 0; l < 3; ++l) {
        const float* w    = (const float*)d_in[1 + 5 * l];
        const float* bias = (const float*)d_in[2 + 5 * l];
        const float* wci  = (const float*)d_in[3 + 5 * l];
        const float* wcf  = (const float*)d_in[4 + 5 * l];
        const float* wco  = (const float*)d_in[5 + 5 * l];
        const u16* inl = (l == 0) ? Yp2 : (l == 1 ? Yp1 : Yp2); // layer-1 overwrites Yp2(=Xp) only after Xp fully consumed
        u16* Ycur      = (l == 0) ? Yp1 : (l == 1 ? Yp2 : Yp1);

        repack_w<<<9216, 256, 0, stream>>>(w, Wx, Wh);

        for (int t = 0; t < T_STEPS; ++t) {
            if ((t & 1) == 0)   // x-part for timesteps t, t+1: N = 4096 (store)
                conv_gemm<true><<<dim3(32, 16), 512, 0, stream>>>(
                    Wx, inl, t, Zx, 4096);
            if (t > 0)          // h-part on H_{t-1}: N = 2048, accumulate into Zx
                conv_gemm<false><<<dim3(16, 16), 512, 0, stream>>>(
                    Wh, Ycur, t - 1, Zx + (size_t)(t & 1) * 2048, 4096);
            float* outp = (l == 2 && t == T_STEPS - 1) ? (float*)d_out : nullptr;
            gates_kernel<<<dim3(8, 32, 2), 256, 0, stream>>>(
                Zx, (t & 1) * 2048, bias, wci, wcf, wco,
                Cbuf, (t == 0) ? 1 : 0, Ycur, t, outp);
        }
    }
}

// Round 4
// 2213.686 us; speedup vs baseline: 1.8550x; 1.0235x over previous
//
#include <hip/hip_runtime.h>

typedef unsigned short u16;
typedef __bf16 bf16x8 __attribute__((ext_vector_type(8)));
typedef float f32x4 __attribute__((ext_vector_type(4)));

#define T_STEPS 8
#define PLANE 1156            // 34*34 padded spatial positions
#define ROWB 2176             // 34 * 32ch * 2B : bytes per padded row in LDS tile

__device__ __forceinline__ u16 f2bf(float f) {
    unsigned u = __float_as_uint(f);
    return (u16)((u + 0x7fff + ((u >> 16) & 1)) >> 16);
}
__device__ __forceinline__ float sigmoidf(float x) {
    return 1.f / (1.f + expf(-x));
}
// async global->LDS, 16B per lane. LDS dest must be base + lane*16 (linear).
__device__ __forceinline__ void gl_lds16(const void* g, void* l) {
    __builtin_amdgcn_global_load_lds(
        (const __attribute__((address_space(1))) void*)g,
        (__attribute__((address_space(3))) void*)l, 16, 0, 0);
}

// ---------------------------------------------------------------------------
// Repack conv_w (fp32) [2048][1024][3][3] -> bf16 GEMM layouts, K reordered
// ci-chunk-major: kt = cc*9 + r.
// x-part: [co_blk(8)][kt(144)][quad(4)][co_in(256)][j(8)]   (BM=256)
// h-part: [co_blk(16)][kt(144)][quad(4)][co_in(128)][j(8)]  (BM=128)
// ---------------------------------------------------------------------------
__global__ void repack_w(const float* __restrict__ w,
                         u16* __restrict__ wx, u16* __restrict__ wh) {
    int g = blockIdx.x * 256 + threadIdx.x;   // 2 * 1,179,648
    const int HALF = 1179648;
    int part = g >= HALF;
    int gg = part ? g - HALF : g;
    int co_in, co_blk, quad, kt, co; u16* dst;
    if (!part) {                               // x: 8 x 144 x 4 x 256
        co_in = gg & 255; gg >>= 8;
        quad  = gg & 3;   gg >>= 2;
        kt = gg % 144; co_blk = gg / 144;
        co = co_blk * 256 + co_in;
        dst = wx + ((((size_t)co_blk * 144 + kt) * 4 + quad) * 256 + co_in) * 8;
    } else {                                   // h: 16 x 144 x 4 x 128
        co_in = gg & 127; gg >>= 7;
        quad  = gg & 3;   gg >>= 2;
        kt = gg % 144; co_blk = gg / 144;
        co = co_blk * 128 + co_in;
        dst = wh + ((((size_t)co_blk * 144 + kt) * 4 + quad) * 128 + co_in) * 8;
    }
    int cc = kt / 9, r = kt - cc * 9;          // chunk, tap
    int ci = cc * 32 + quad * 8;
    const float* src = w + ((size_t)co * 1024 + (size_t)part * 512 + ci) * 9 + r;
    union { u16 u[8]; uint4 v; } tmp;
#pragma unroll
    for (int j = 0; j < 8; j++) tmp.u[j] = f2bf(src[(size_t)j * 9]);
    *(uint4*)dst = tmp.v;
}

// ---------------------------------------------------------------------------
// x [2][512][8][32][32] f32 -> Xp [b*8+t][34][34][512] bf16 (interior only;
// border pre-zeroed by memset). Reads coalesced along x.
// ---------------------------------------------------------------------------
__global__ __launch_bounds__(256) void pretransform_x(
    const float* __restrict__ x, u16* __restrict__ Xp) {
    const int bt = blockIdx.x >> 5;            // b*8+t
    const int y  = blockIdx.x & 31;
    const int b  = bt >> 3;
    const int xx = threadIdx.x & 31, cg0 = threadIdx.x >> 5;
    const float* src = x + ((size_t)(b * 512) * T_STEPS + (bt & 7)) * 1024
                         + y * 32 + xx;
    u16* dst = Xp + (((size_t)bt * 34 + y + 1) * 34 + (xx + 1)) * 512;
#pragma unroll
    for (int it = 0; it < 8; ++it) {
        const int cig = cg0 + it * 8;          // 0..63 (8-channel group)
        union { u16 u[8]; uint4 v; } pk;
#pragma unroll
        for (int j = 0; j < 8; ++j)
            pk.u[j] = f2bf(src[(size_t)(cig * 8 + j) * 8192]);
        *(uint4*)(dst + cig * 8) = pk.v;
    }
}

// ---------------------------------------------------------------------------
// Implicit-conv GEMM.  A (weights) global->VGPR 3-deep ring (+2 taps, L2-
// resident via XCD swizzle).  B chunk tile in LDS (dbuf per chunk), fragments
// register-double-buffered across taps so ds_read latency hides under MFMAs.
// One counted vmcnt + s_barrier per chunk (never drains prefetches).
//   XMODE (x-part): BM=256, MF=4 A-frags/wave, grid 8 co x 32 n, N=4096
//                   (2t x 2b: plane=n0>>10, b=plane&1, t=t0+(plane>>1)); store.
//   !XMODE (h-part): BM=128, MF=2, grid 16 co x 16 n, N=2048 (plane=b); +=.
// vmcnt derivation (per thread): at chunk-head barrier the newest loads are
// the A-prefetches issued after B(cc) (7 taps x MF); keeping <=7*MF drains
// own B(cc) staging loads (1 or 2, oldest).  First chunk: prologue = B then
// 2*MF A-loads -> vmcnt(2*MF).
// ---------------------------------------------------------------------------
#define READB(dstv, btcp, rr) {                                              \
    const int ry_ = (rr) / 3, rx_ = (rr) % 3;                                \
    dstv[0] = *(const bf16x8*)((btcp) + wnrow + (0 + ry_) * ROWB + colb[0][rx_]); \
    dstv[1] = *(const bf16x8*)((btcp) + wnrow + (0 + ry_) * ROWB + colb[1][rx_]); \
    dstv[2] = *(const bf16x8*)((btcp) + wnrow + (1 + ry_) * ROWB + colb[0][rx_]); \
    dstv[3] = *(const bf16x8*)((btcp) + wnrow + (1 + ry_) * ROWB + colb[1][rx_]); }

template<bool XMODE>
__global__ __launch_bounds__(512, 2) void conv_gemm(
    const u16* __restrict__ Wp, const u16* __restrict__ Xp, int t0,
    float* __restrict__ Z, int ldz) {
    constexpr int MF   = XMODE ? 4 : 2;       // A frags per wave
    constexpr int COIN = XMODE ? 256 : 128;   // co per block
    constexpr int KSTR = 4 * COIN;            // uint4 per kt

    __shared__ __align__(16) u16 Bt[2][6528]; // 25.5 KB chunk dbuf

    const int tid = threadIdx.x;
    const int bid = blockIdx.y * (XMODE ? 32 : 16) + blockIdx.x;  // 0..255
    const int swz = (bid & 7) * 32 + (bid >> 3);                  // XCD chunks
    const int co_blk = XMODE ? (swz >> 5) : (swz >> 4);
    const int nblk   = XMODE ? (swz & 31) : (swz & 15);
    const int n0 = nblk * 128;

    const int wave = tid >> 6, lane = tid & 63;
    const int wm = wave >> 1, wn = wave & 1;          // 4 x 2 wave grid
    const int q_l = lane >> 4, m_l = lane & 15;

    const int plane = n0 >> 10;
    const int bb_ = XMODE ? (plane & 1) : plane;
    const int tt  = XMODE ? (t0 + (plane >> 1)) : t0;
    const int pyb = (n0 & 1023) >> 5;                 // first output row
    const u16* pbase = Xp + (size_t)(bb_ * T_STEPS + tt) * PLANE * 512;

    // --- B-tile staging: 816 16B chunks = [pos(6*34)][slot(4)] ---
    const int c0 = tid;
    const int p0 = c0 >> 2, sl0 = c0 & 3;
    const int yl0 = p0 / 34, xl0 = p0 - yl0 * 34;
    const int src0 = ((pyb + yl0) * 34 + xl0) * 512 + ((sl0 ^ ((xl0 >> 1) & 3)) << 3);
    const int c1 = 512 + tid;
    const int p1 = c1 >> 2, sl1 = c1 & 3;
    const int yl1 = p1 / 34, xl1 = p1 - yl1 * 34;
    const int src1 = ((pyb + yl1) * 34 + xl1) * 512 + ((sl1 ^ ((xl1 >> 1) & 3)) << 3);
    const bool do1 = tid < 304;                       // 816 - 512

    // A-fragment base: [kt][quad][co_in] uint4; frag mt at +mt*16
    const uint4* Aq = (const uint4*)Wp + (size_t)co_blk * 144 * KSTR
                      + q_l * COIN + wm * (MF * 16) + m_l;

    // B-fragment column byte offsets (read swizzle matches source swizzle)
    int colb[2][3];
#pragma unroll
    for (int xh = 0; xh < 2; xh++)
#pragma unroll
        for (int rx = 0; rx < 3; rx++) {
            int xl = xh * 16 + m_l + rx;              // 0..33
            colb[xh][rx] = xl * 64 + ((q_l ^ ((xl >> 1) & 3)) << 4);
        }
    const int wnrow = wn * 2 * ROWB;

    f32x4 acc[MF][4];
#pragma unroll
    for (int i = 0; i < MF; i++)
#pragma unroll
        for (int j = 0; j < 4; j++) acc[i][j] = (f32x4){0.f, 0.f, 0.f, 0.f};

    bf16x8 areg[3][MF], breg[2][4];

    // prologue: B(0) staged; A(0),A(1) into ring slots 0,1
    gl_lds16(pbase + src0, &Bt[0][c0 * 8]);
    if (do1) gl_lds16(pbase + src1, &Bt[0][c1 * 8]);
#pragma unroll
    for (int mt = 0; mt < MF; ++mt) {
        areg[0][mt] = *(const bf16x8*)(Aq + mt * 16);
        areg[1][mt] = *(const bf16x8*)(Aq + KSTR + mt * 16);
    }

    for (int cc = 0; cc < 16; ++cc) {
        const int cb = cc & 1;
        const char* btc = (const char*)&Bt[cb][0];
        asm volatile("" ::: "memory");
        if (cc == 0) {
            if (XMODE) asm volatile("s_waitcnt vmcnt(8)" ::: "memory");
            else       asm volatile("s_waitcnt vmcnt(4)" ::: "memory");
        } else {
            if (XMODE) asm volatile("s_waitcnt vmcnt(28)" ::: "memory");
            else       asm volatile("s_waitcnt vmcnt(14)" ::: "memory");
        }
        __builtin_amdgcn_s_barrier();
        asm volatile("" ::: "memory");        // no LDS reads hoist above
        READB(breg[0], btc, 0);               // tap 0 frags (short lgkm stall)
#pragma unroll
        for (int r = 0; r < 9; ++r) {
            const int kt = cc * 9 + r;
            // A prefetch +2 taps into ring slot (static idx; 9%3==0)
            if (cc < 15 || r < 7) {
#pragma unroll
                for (int mt = 0; mt < MF; ++mt)
                    areg[(r + 2) % 3][mt] =
                        *(const bf16x8*)(Aq + (size_t)(kt + 2) * KSTR + mt * 16);
            }
            // next B chunk (after this chunk's barrier -> WAR-safe)
            if (r == 1 && cc < 15) {
                const u16* gs = pbase + (cc + 1) * 32;
                gl_lds16(gs + src0, &Bt[cb ^ 1][c0 * 8]);
                if (do1) gl_lds16(gs + src1, &Bt[cb ^ 1][c1 * 8]);
            }
            // B-frag register prefetch for next tap (hides ds_read latency)
            if (r < 8) READB(breg[(r + 1) & 1], btc, (r + 1));
            __builtin_amdgcn_s_setprio(1);
#pragma unroll
            for (int mt = 0; mt < MF; ++mt) {
                acc[mt][0] = __builtin_amdgcn_mfma_f32_16x16x32_bf16(
                    areg[r % 3][mt], breg[r & 1][0], acc[mt][0], 0, 0, 0);
                acc[mt][1] = __builtin_amdgcn_mfma_f32_16x16x32_bf16(
                    areg[r % 3][mt], breg[r & 1][1], acc[mt][1], 0, 0, 0);
                acc[mt][2] = __builtin_amdgcn_mfma_f32_16x16x32_bf16(
                    areg[r % 3][mt], breg[r & 1][2], acc[mt][2], 0, 0, 0);
                acc[mt][3] = __builtin_amdgcn_mfma_f32_16x16x32_bf16(
                    areg[r % 3][mt], breg[r & 1][3], acc[mt][3], 0, 0, 0);
            }
            __builtin_amdgcn_s_setprio(0);
        }
    }

    // Epilogue: C/D layout col=lane&15 (n), row=(lane>>4)*4+reg (m)
#pragma unroll
    for (int mt = 0; mt < MF; mt++)
#pragma unroll
        for (int nt = 0; nt < 4; nt++)
#pragma unroll
            for (int reg = 0; reg < 4; reg++) {
                int co = co_blk * COIN + wm * (MF * 16) + mt * 16 + q_l * 4 + reg;
                int n  = n0 + wn * 64 + nt * 16 + m_l;
                float* zp = &Z[(size_t)co * ldz + n];
                if (XMODE) *zp = acc[mt][nt][reg];
                else       *zp += acc[mt][nt][reg];
            }
}

// ---------------------------------------------------------------------------
// Gates: fp32 math; z = Zx (x-part, with h-part pre-accumulated for t>0).
// Writes Y into padded channel-last layout via LDS transpose; out coalesced.
// grid: (8 s-tiles of 128, 32 co-tiles of 16, 2 b), 256 threads.
// ---------------------------------------------------------------------------
__global__ __launch_bounds__(256) void gates_kernel(
    const float* __restrict__ zx, int nxoff,
    const float* __restrict__ bias,
    const float* __restrict__ wci, const float* __restrict__ wcf,
    const float* __restrict__ wco,
    float* __restrict__ C, int is_first,
    u16* __restrict__ Yp, int t,
    float* __restrict__ outp) {
    __shared__ u16 Hs[16][136];
    const int tid = threadIdx.x;
    const int s0  = blockIdx.x * 128;
    const int co0 = blockIdx.y * 16;
    const int b   = blockIdx.z;
    const int sl = tid & 127, ch = tid >> 7;
    const int s = s0 + sl;

#pragma unroll
    for (int k = 0; k < 8; ++k) {
        const int co = co0 + k * 2 + ch;
        const size_t zi_ = (size_t)co * 4096 + nxoff + b * 1024 + s;
        float zi = zx[zi_]                       + bias[co];
        float zf = zx[zi_ + (size_t)512 * 4096]  + bias[co + 512];
        float zc = zx[zi_ + (size_t)1024 * 4096] + bias[co + 1024];
        float zo = zx[zi_ + (size_t)1536 * 4096] + bias[co + 1536];
        const size_t ci_ = ((size_t)b * 512 + co) * 1024 + s;
        float Cp = is_first ? 0.f : C[ci_];
        const int ps = co * 1024 + s;
        float gi = sigmoidf(zi + wci[ps] * Cp);
        float gf = sigmoidf(zf + wcf[ps] * Cp);
        float Cn = gf * Cp + gi * fmaxf(zc, 0.f);
        float go = sigmoidf(zo + wco[ps] * Cn);
        float Hn = go * fmaxf(Cn, 0.f);
        C[ci_] = Cn;
        Hs[k * 2 + ch][sl] = f2bf(Hn);
        if (outp) outp[ci_] = sigmoidf(Hn);
    }
    __syncthreads();
    // transpose-write: 16 channels contiguous per spatial position
    const int sl2 = tid & 127, half = tid >> 7;
    const int s2 = s0 + sl2;
    const int yp = (s2 >> 5) + 1, xp = (s2 & 31) + 1;
    u16* dst = Yp + (((size_t)(b * T_STEPS + t) * 34 + yp) * 34 + xp) * 512
                  + co0 + half * 8;
    union { u16 u[8]; uint4 v; } pk;
#pragma unroll
    for (int j = 0; j < 8; ++j) pk.u[j] = Hs[half * 8 + j][sl2];
    *(uint4*)dst = pk.v;
}

// ---------------------------------------------------------------------------
extern "C" void kernel_launch(void* const* d_in, const int* in_sizes, int n_in,
                              void* d_out, int out_size, void* d_ws, size_t ws_size,
                              hipStream_t stream) {
    const float* x = (const float*)d_in[0];

    char* ws = (char*)d_ws;
    size_t off = 0;
    auto carve = [&](size_t bytes) { char* p = ws + off; off += (bytes + 255) & ~(size_t)255; return p; };

    u16*   Wx   = (u16*)  carve((size_t)8 * 144 * 8192 * 2);    // 18.9 MB
    u16*   Wh   = (u16*)  carve((size_t)16 * 144 * 4096 * 2);   // 18.9 MB
    float* Zx   = (float*)carve((size_t)2048 * 4096 * 4);       // 33.6 MB (h accumulates in-place)
    float* Cbuf = (float*)carve((size_t)2 * 512 * 1024 * 4);    //  4.2 MB
    const size_t PADB = (size_t)16 * PLANE * 512 * 2;           // 18.9 MB padded Y/X
    u16*   Yp1  = (u16*)  carve(PADB);
    u16*   Yp2  = (u16*)  carve(PADB);                          // doubles as Xp (layer 0 input)
    (void)ws_size; (void)in_sizes; (void)n_in; (void)out_size;  // ~113 MB total

    hipMemsetAsync(Yp1, 0, PADB, stream);                       // zero borders
    hipMemsetAsync(Yp2, 0, PADB, stream);
    pretransform_x<<<512, 256, 0, stream>>>(x, Yp2);

    for (int l = 0; l < 3; ++l) {
        const float* w    = (const float*)d_in[1 + 5 * l];
        const float* bias = (const float*)d_in[2 + 5 * l];
        const float* wci  = (const float*)d_in[3 + 5 * l];
        const float* wcf  = (const float*)d_in[4 + 5 * l];
        const float* wco  = (const float*)d_in[5 + 5 * l];
        const u16* inl = (l == 0) ? Yp2 : (l == 1 ? Yp1 : Yp2); // layer-1 overwrites Yp2(=Xp) only after Xp fully consumed
        u16* Ycur      = (l == 0) ? Yp1 : (l == 1 ? Yp2 : Yp1);

        repack_w<<<9216, 256, 0, stream>>>(w, Wx, Wh);

        for (int t = 0; t < T_STEPS; ++t) {
            if ((t & 1) == 0)   // x-part for timesteps t, t+1: N = 4096 (store)
                conv_gemm<true><<<dim3(32, 8), 512, 0, stream>>>(
                    Wx, inl, t, Zx, 4096);
            if (t > 0)          // h-part on H_{t-1}: N = 2048, accumulate into Zx
                conv_gemm<false><<<dim3(16, 16), 512, 0, stream>>>(
                    Wh, Ycur, t - 1, Zx + (size_t)(t & 1) * 2048, 4096);
            float* outp = (l == 2 && t == T_STEPS - 1) ? (float*)d_out : nullptr;
            gates_kernel<<<dim3(8, 32, 2), 256, 0, stream>>>(
                Zx, (t & 1) * 2048, bias, wci, wcf, wco,
                Cbuf, (t == 0) ? 1 : 0, Ycur, t, outp);
        }
    }
}